// Round 3
// baseline (318.002 us; speedup 1.0000x reference)
//
#include <hip/hip_runtime.h>
#include <hip/hip_bf16.h>

#define N 8192
#define Dd 128
#define NT 16   // column tiles per block (strip-mined)

typedef short short8 __attribute__((ext_vector_type(8)));
typedef float floatx4 __attribute__((ext_vector_type(4)));

// round-to-nearest-even fp32 -> bf16 (no NaN in inputs)
static __device__ inline unsigned short f2bf(float f) {
    unsigned int u = __float_as_uint(f);
    return (unsigned short)((u + 0x7fffu + ((u >> 16) & 1u)) >> 16);
}
static __device__ inline float bf2f(unsigned short b) {
    return __uint_as_float(((unsigned int)b) << 16);
}

// One wave per row: convert to bf16, store, and compute row norm of the
// *rounded* values so the gram diagonal cancels exactly.
__global__ __launch_bounds__(256) void prep_kernel(const float* __restrict__ z,
                                                   unsigned short* __restrict__ zb,
                                                   float* __restrict__ sq) {
    int row  = blockIdx.x * 4 + (threadIdx.x >> 6);
    int lane = threadIdx.x & 63;
    float2 v = ((const float2*)z)[row * 64 + lane];
    unsigned short b0 = f2bf(v.x);
    unsigned short b1 = f2bf(v.y);
    float f0 = bf2f(b0), f1 = bf2f(b1);
    ushort2 st; st.x = b0; st.y = b1;
    ((ushort2*)zb)[row * 64 + lane] = st;
    float s = f0 * f0 + f1 * f1;
    #pragma unroll
    for (int off = 32; off > 0; off >>= 1) s += __shfl_down(s, off, 64);
    if (lane == 0) sq[row] = s;
}

// R7: R6 structure + NON-TEMPORAL output stores. Accounting across R4/R5/R6
// shows pairsim is HBM-bound at (writes + staging reads): the 268 MB write
// stream churns each XCD's 4 MiB L2 every ~2 us, so the 2 MiB zb never stays
// resident and every staging read is a compulsory HBM fetch (R6: 278 MB read
// + 268 MB write = 87 us predicted ~= 88-91 measured). nt stores stream the
// output past L2 without allocating -> zb stays L2-resident -> staging reads
// collapse to ~compulsory -> pairsim ~= write roofline ~48-55 us.
// (R3's nt regression was in the phase-serialized one-tile structure where
// store-ack latency piled into per-tile barrier drains; here the drain
// overlaps a full iteration of compute+store.)
__global__ __launch_bounds__(256, 4) void pairsim_kernel(const unsigned short* __restrict__ zb,
                                                         const float* __restrict__ sq,
                                                         float* __restrict__ out) {
    __shared__ unsigned short bufA[64 * 128];   // A panel, then B write buffer
    __shared__ unsigned short bufB[64 * 128];   // B double-buffer partner

    int t = threadIdx.x;
    int w = t >> 6, lane = t & 63;
    int rowBase   = blockIdx.y * 64;
    int chunkBase = blockIdx.x * (NT * 64);

    int wr = (w >> 1) * 32, wc = (w & 1) * 32;  // 2x2 waves -> 32x32 each
    int m = lane & 15, quad = lane >> 4;

    // Staging geometry: wave w stages panel rows 16w..16w+15, 4 instrs (q).
    // Linear LDS dest (lane l -> row 16w+4q+(l>>4), slot l&15); global source
    // chunk pre-swizzled so slot s of row r holds chunk s^(r&15).
    int srow_[4], schk_[4];
    #pragma unroll
    for (int q = 0; q < 4; q++) {
        srow_[q] = 16 * w + 4 * q + (lane >> 4);
        schk_[q] = (lane & 15) ^ (4 * q + (lane >> 4));
    }
    const char* zbB = (const char*)zb;

#define STAGE(panel, growbase)                                                      \
    {                                                                               \
        _Pragma("unroll")                                                           \
        for (int q = 0; q < 4; q++) {                                               \
            const void* gsrc = zbB + (((size_t)((growbase) + srow_[q])) << 8)       \
                                   + ((size_t)schk_[q] << 4);                       \
            __builtin_amdgcn_global_load_lds(                                       \
                (const __attribute__((address_space(1))) void*)gsrc,                \
                (__attribute__((address_space(3))) void*)((char*)(panel) +          \
                                                          (16 * w + 4 * q) * 256),  \
                16, 0, 0);                                                          \
        }                                                                           \
    }

    // ---- prologue: A panel -> bufA, B tile 0 -> bufB ----
    STAGE(bufA, rowBase);
    STAGE(bufB, chunkBase);
    __syncthreads();   // vmcnt(0) drain: both panels resident

    // A fragments -> registers for the whole strip (chunk c lives at slot c^m)
    short8 af[2][4];
    #pragma unroll
    for (int i = 0; i < 2; i++)
        #pragma unroll
        for (int ks = 0; ks < 4; ks++) {
            int c = ks * 4 + quad;
            af[i][ks] = *(const short8*)&bufA[(wr + i * 16 + m) * 128 + ((c ^ m) * 8)];
        }

    float sr_[2][4];
    #pragma unroll
    for (int i = 0; i < 2; i++)
        #pragma unroll
        for (int r = 0; r < 4; r++)
            sr_[i][r] = sq[rowBase + wr + i * 16 + quad * 4 + r];

    // Per iteration: BAR -> ds_read B[k] -> issue stage B[k+1] -> MFMA ->
    // exp + nt-store. ds_reads precede the stage so all staging is quiesced
    // at each barrier (no compiler alias-vmcnt mid-iteration).
#define ITER(k, RBUF, WBUF, DO_STAGE)                                               \
    {                                                                               \
        __syncthreads();                                                            \
        short8 bfv[2][4];                                                           \
        _Pragma("unroll")                                                           \
        for (int ks = 0; ks < 4; ks++) {                                            \
            int c = ks * 4 + quad;                                                  \
            bfv[0][ks] = *(const short8*)&(RBUF)[(wc + m) * 128 + ((c ^ m) * 8)];   \
            bfv[1][ks] = *(const short8*)&(RBUF)[(wc + 16 + m) * 128 + ((c ^ m) * 8)]; \
        }                                                                           \
        if (DO_STAGE) STAGE(WBUF, chunkBase + ((k) + 1) * 64);                      \
        floatx4 zero = {0.f, 0.f, 0.f, 0.f};                                        \
        floatx4 acc[2][2];                                                          \
        acc[0][0] = zero; acc[0][1] = zero; acc[1][0] = zero; acc[1][1] = zero;     \
        _Pragma("unroll")                                                           \
        for (int ks = 0; ks < 4; ks++) {                                            \
            _Pragma("unroll")                                                       \
            for (int i = 0; i < 2; i++)                                             \
                _Pragma("unroll")                                                   \
                for (int j = 0; j < 2; j++)                                         \
                    acc[i][j] = __builtin_amdgcn_mfma_f32_16x16x32_bf16(            \
                        af[i][ks], bfv[j][ks], acc[i][j], 0, 0, 0);                 \
        }                                                                           \
        int c0 = chunkBase + (k) * 64;                                              \
        float sc0 = sq[c0 + wc + m];                                                \
        float sc1 = sq[c0 + wc + 16 + m];                                           \
        _Pragma("unroll")                                                           \
        for (int i = 0; i < 2; i++) {                                               \
            _Pragma("unroll")                                                       \
            for (int r = 0; r < 4; r++) {                                           \
                int row = rowBase + wr + i * 16 + quad * 4 + r;                     \
                float sr = sr_[i][r];                                               \
                float g0 = acc[i][0][r];                                            \
                float g1 = acc[i][1][r];                                            \
                float e0 = fminf(2.0f * g0 - sr - sc0, 0.0f);                       \
                float e1 = fminf(2.0f * g1 - sr - sc1, 0.0f);                       \
                size_t ro = (size_t)row * N;                                        \
                __builtin_nontemporal_store(__expf(e0), &out[ro + (c0 + wc + m)]);  \
                __builtin_nontemporal_store(__expf(e1), &out[ro + (c0 + wc + 16 + m)]); \
            }                                                                       \
        }                                                                           \
    }

    #pragma unroll 1
    for (int kk = 0; kk < NT; kk += 2) {
        ITER(kk,     bufB, bufA, 1);
        ITER(kk + 1, bufA, bufB, (kk < NT - 2));
    }
#undef ITER
#undef STAGE
}

extern "C" void kernel_launch(void* const* d_in, const int* in_sizes, int n_in,
                              void* d_out, int out_size, void* d_ws, size_t ws_size,
                              hipStream_t stream) {
    const float* z = (const float*)d_in[0];
    unsigned short* zb = (unsigned short*)d_ws;                       // 2 MB bf16 copy
    float* sqv = (float*)((char*)d_ws + (size_t)N * Dd * sizeof(unsigned short)); // 32 KB norms
    float* out = (float*)d_out;

    prep_kernel<<<N / 4, 256, 0, stream>>>(z, zb, sqv);
    pairsim_kernel<<<dim3(8, 128), 256, 0, stream>>>(zb, sqv, out);
}

// Round 4
// 271.574 us; speedup vs baseline: 1.1710x; 1.1710x over previous
//
#include <hip/hip_runtime.h>
#include <hip/hip_bf16.h>

#define N 8192
#define Dd 128
#define NT 16   // column tiles per block (strip-mined)

typedef short short8 __attribute__((ext_vector_type(8)));
typedef float floatx4 __attribute__((ext_vector_type(4)));

// round-to-nearest-even fp32 -> bf16 (no NaN in inputs)
static __device__ inline unsigned short f2bf(float f) {
    unsigned int u = __float_as_uint(f);
    return (unsigned short)((u + 0x7fffu + ((u >> 16) & 1u)) >> 16);
}
static __device__ inline float bf2f(unsigned short b) {
    return __uint_as_float(((unsigned int)b) << 16);
}

// One wave per row: convert to bf16, store, and compute row norm of the
// *rounded* values so the gram diagonal cancels exactly.
__global__ __launch_bounds__(256) void prep_kernel(const float* __restrict__ z,
                                                   unsigned short* __restrict__ zb,
                                                   float* __restrict__ sq) {
    int row  = blockIdx.x * 4 + (threadIdx.x >> 6);
    int lane = threadIdx.x & 63;
    float2 v = ((const float2*)z)[row * 64 + lane];
    unsigned short b0 = f2bf(v.x);
    unsigned short b1 = f2bf(v.y);
    float f0 = bf2f(b0), f1 = bf2f(b1);
    ushort2 st; st.x = b0; st.y = b1;
    ((ushort2*)zb)[row * 64 + lane] = st;
    float s = f0 * f0 + f1 * f1;
    #pragma unroll
    for (int off = 32; off > 0; off >>= 1) s += __shfl_down(s, off, 64);
    if (lane == 0) sq[row] = s;
}

// R8: R6 pipeline with BM=128 row strips. R6 ran at 6.0 TB/s combined
// (278 MB reads + 268 MB writes in 91 us) = ~95% of achievable HBM BW --
// traffic-bound, not schedule-bound. Staging traffic = N^2*256B*(1/BM+1/BN);
// doubling BM to 128 cuts reads to 147 MB (512 blocks x [32KB A + 256KB B]).
// A panel staged once into bufA, A-frags held in 64 VGPRs for the whole
// strip; bufA is then recycled as one of the B double-buffers. Cacheable
// scattered-dword stores (R3+R7: nt stores demote the 64B-per-quad pattern
// to sub-line HBM granules -- twice-confirmed regression).
__global__ __launch_bounds__(256, 2) void pairsim_kernel(const unsigned short* __restrict__ zb,
                                                         const float* __restrict__ sq,
                                                         float* __restrict__ out) {
    __shared__ unsigned short bufA[128 * 128];  // 32 KB: A panel, then B write buffer
    __shared__ unsigned short bufB[64 * 128];   // 16 KB: B double-buffer partner

    int t = threadIdx.x;
    int w = t >> 6, lane = t & 63;
    int rowBase   = blockIdx.y * 128;
    int chunkBase = blockIdx.x * (NT * 64);

    int wr = (w >> 1) * 64, wc = (w & 1) * 32;  // 2x2 waves -> 64x32 each
    int m = lane & 15, quad = lane >> 4;

    // Staging: wave w stages RW rows starting at RW*w, QN instrs of 4 rows
    // each. Linear LDS dest (lane l -> row +4q+(l>>4), slot l&15); global
    // source chunk pre-swizzled so slot s of row r holds chunk s^(r&15).
    const char* zbB = (const char*)zb;

#define STAGE(panel, growbase, QN, RW)                                              \
    {                                                                               \
        _Pragma("unroll")                                                           \
        for (int q = 0; q < (QN); q++) {                                            \
            int srow = (RW) * w + 4 * q + (lane >> 4);                              \
            int schk = (lane & 15) ^ ((4 * q + (lane >> 4)) & 15);                  \
            const void* gsrc = zbB + (((size_t)((growbase) + srow)) << 8)           \
                                   + ((size_t)schk << 4);                           \
            __builtin_amdgcn_global_load_lds(                                       \
                (const __attribute__((address_space(1))) void*)gsrc,                \
                (__attribute__((address_space(3))) void*)((char*)(panel) +          \
                                           ((RW) * w + 4 * q) * 256),               \
                16, 0, 0);                                                          \
        }                                                                           \
    }

    // ---- prologue: A panel (128 rows) -> bufA, B tile 0 (64 rows) -> bufB ----
    STAGE(bufA, rowBase, 8, 32);
    STAGE(bufB, chunkBase, 4, 16);
    __syncthreads();   // vmcnt(0) drain: both panels resident

    // A fragments -> registers for the whole strip (chunk c lives at slot c^m)
    short8 af[4][4];
    #pragma unroll
    for (int i = 0; i < 4; i++)
        #pragma unroll
        for (int ks = 0; ks < 4; ks++) {
            int c = ks * 4 + quad;
            af[i][ks] = *(const short8*)&bufA[(wr + i * 16 + m) * 128 + ((c ^ m) * 8)];
        }

    float sr_[4][4];
    #pragma unroll
    for (int i = 0; i < 4; i++)
        #pragma unroll
        for (int r = 0; r < 4; r++)
            sr_[i][r] = sq[rowBase + wr + i * 16 + quad * 4 + r];

    // Per iteration: BAR -> ds_read B[k] -> issue stage B[k+1] -> MFMA ->
    // exp+store. ds_reads precede the stage so all staging is quiesced at
    // each barrier (no compiler alias-vmcnt mid-iteration). BAR(k) drains
    // af/B ds_reads (lgkm) before the stage overwrites, and S(k) (vmcnt)
    // before R(k) -- __syncthreads semantics are the correctness guarantee.
#define ITER(k, RBUF, WBUF, DO_STAGE)                                               \
    {                                                                               \
        __syncthreads();                                                            \
        short8 bfv[2][4];                                                           \
        _Pragma("unroll")                                                           \
        for (int ks = 0; ks < 4; ks++) {                                            \
            int c = ks * 4 + quad;                                                  \
            bfv[0][ks] = *(const short8*)&(RBUF)[(wc + m) * 128 + ((c ^ m) * 8)];   \
            bfv[1][ks] = *(const short8*)&(RBUF)[(wc + 16 + m) * 128 + ((c ^ m) * 8)]; \
        }                                                                           \
        if (DO_STAGE) STAGE(WBUF, chunkBase + ((k) + 1) * 64, 4, 16);               \
        floatx4 zero = {0.f, 0.f, 0.f, 0.f};                                        \
        floatx4 acc[4][2];                                                          \
        _Pragma("unroll")                                                           \
        for (int i = 0; i < 4; i++) { acc[i][0] = zero; acc[i][1] = zero; }         \
        _Pragma("unroll")                                                           \
        for (int ks = 0; ks < 4; ks++) {                                            \
            _Pragma("unroll")                                                       \
            for (int i = 0; i < 4; i++)                                             \
                _Pragma("unroll")                                                   \
                for (int j = 0; j < 2; j++)                                         \
                    acc[i][j] = __builtin_amdgcn_mfma_f32_16x16x32_bf16(            \
                        af[i][ks], bfv[j][ks], acc[i][j], 0, 0, 0);                 \
        }                                                                           \
        int c0 = chunkBase + (k) * 64;                                              \
        float sc0 = sq[c0 + wc + m];                                                \
        float sc1 = sq[c0 + wc + 16 + m];                                           \
        _Pragma("unroll")                                                           \
        for (int i = 0; i < 4; i++) {                                               \
            _Pragma("unroll")                                                       \
            for (int r = 0; r < 4; r++) {                                           \
                int row = rowBase + wr + i * 16 + quad * 4 + r;                     \
                float sr = sr_[i][r];                                               \
                float g0 = acc[i][0][r];                                            \
                float g1 = acc[i][1][r];                                            \
                float e0 = fminf(2.0f * g0 - sr - sc0, 0.0f);                       \
                float e1 = fminf(2.0f * g1 - sr - sc1, 0.0f);                       \
                size_t ro = (size_t)row * N;                                        \
                out[ro + (c0 + wc + m)]      = __expf(e0);                          \
                out[ro + (c0 + wc + 16 + m)] = __expf(e1);                          \
            }                                                                       \
        }                                                                           \
    }

    #pragma unroll 1
    for (int kk = 0; kk < NT; kk += 2) {
        ITER(kk,     bufB, bufA, 1);
        ITER(kk + 1, bufA, bufB, (kk < NT - 2));
    }
#undef ITER
#undef STAGE
}

extern "C" void kernel_launch(void* const* d_in, const int* in_sizes, int n_in,
                              void* d_out, int out_size, void* d_ws, size_t ws_size,
                              hipStream_t stream) {
    const float* z = (const float*)d_in[0];
    unsigned short* zb = (unsigned short*)d_ws;                       // 2 MB bf16 copy
    float* sqv = (float*)((char*)d_ws + (size_t)N * Dd * sizeof(unsigned short)); // 32 KB norms
    float* out = (float*)d_out;

    prep_kernel<<<N / 4, 256, 0, stream>>>(z, zb, sqv);
    pairsim_kernel<<<dim3(8, 64), 256, 0, stream>>>(zb, sqv, out);
}